// Round 23
// baseline (303.353 us; speedup 1.0000x reference)
//
#include <hip/hip_runtime.h>
#include <hip/hip_bf16.h>
#include <stdint.h>

// MultiHeadDiffAttention — R23 = R22 (301.7us) + two launch-shape-only changes:
// (1) gemm_fin BMf 128->64: grid 512->1024 blocks (2->4 blk/CU, 8->16 waves/CU)
//     — it was grid-limited, not resource-limited; K=2048 long loop needs TLP.
// (2) prep: cvt3_bf16 + tcvt6 merged into ONE 20480-block launch (1D decode).
// diffattn + gemm_proj byte-identical to R22 (diffattn regalloc-frozen).
// B=2, T=2048, C=1024, H=16, HS=64.

#define T_SEQ 2048

typedef unsigned short u16;
typedef __attribute__((ext_vector_type(8))) short short8;
typedef __attribute__((ext_vector_type(4))) float f32x4;
typedef __attribute__((ext_vector_type(16))) float f32x16;

#define LAMBDA_INIT 0.35550906759096926f
#define ONE_MINUS_LI 0.6444909324090307f
#define SM_SCALE 0.125f
#define LOG2E 1.44269504f

__device__ __forceinline__ u16 f2bf(float f) {
  uint32_t u = __float_as_uint(f);
  return (u16)((u + 0x7FFFu + ((u >> 16) & 1u)) >> 16);
}
__device__ __forceinline__ float b2f(u16 u) {
  return __uint_as_float(((uint32_t)u) << 16);
}
__device__ __forceinline__ short8 ld8(const u16* p) {
  return *reinterpret_cast<const short8*>(p);
}
__device__ __forceinline__ void st8(u16* p, short8 v) {
  *reinterpret_cast<short8*>(p) = v;
}
__device__ __forceinline__ f32x4 mfma16(short8 a, short8 b, f32x4 c) {
  return __builtin_amdgcn_mfma_f32_16x16x32_bf16(a, b, c, 0, 0, 0);
}
__device__ __forceinline__ f32x16 mfma32(short8 a, short8 b, f32x16 c) {
  return __builtin_amdgcn_mfma_f32_32x32x16_bf16(a, b, c, 0, 0, 0);
}
__device__ __forceinline__ uint32_t cvtpk(float lo, float hi_) {
  uint32_t r;
  asm("v_cvt_pk_bf16_f32 %0, %1, %2" : "=v"(r) : "v"(lo), "v"(hi_));
  return r;
}

// ---- prep: cvt3 (q,k,v f32->bf16; ids 0..12287) + tcvt6 (ids 12288..20479) ----
__global__ __launch_bounds__(256) void prep(const float* __restrict__ q,
                                            const float* __restrict__ k,
                                            const float* __restrict__ v,
                                            u16* __restrict__ qkvb, int n,
                                            const float* __restrict__ W0,
                                            const float* __restrict__ W1,
                                            const float* __restrict__ W2,
                                            const float* __restrict__ W3,
                                            const float* __restrict__ Wv,
                                            const float* __restrict__ Wc,
                                            u16* __restrict__ WqkT,
                                            u16* __restrict__ WvT,
                                            u16* __restrict__ WcT) {
  int bid = blockIdx.x;
  if (bid < 12288) {
    int i = (bid * 256 + threadIdx.x) * 4;  // over 3n elems
    const float* src;
    int j = i;
    if (i < n) src = q;
    else if (i < 2 * n) { src = k; j = i - n; }
    else { src = v; j = i - 2 * n; }
    float4 f = *reinterpret_cast<const float4*>(src + j);
    union { u16 u[4]; uint2 v2; } pk;
    pk.u[0] = f2bf(f.x); pk.u[1] = f2bf(f.y); pk.u[2] = f2bf(f.z); pk.u[3] = f2bf(f.w);
    *reinterpret_cast<uint2*>(qkvb + i) = pk.v2;
    return;
  }
  __shared__ float tile[32][33];
  int id = bid - 12288;  // 0..8191
  const float* W; u16* WT; int K, N, n0, k0, outRowOff;
  if (id < 4096) {
    int z = id >> 10, r = id & 1023;
    W = (z == 0) ? W0 : (z == 1) ? W1 : (z == 2) ? W2 : W3;
    WT = WqkT; K = 1024; N = 1024;
    n0 = (r & 31) * 32; k0 = (r >> 5) * 32; outRowOff = z * 1024;
  } else if (id < 6144) {
    int r = id - 4096;
    W = Wv; WT = WvT; K = 1024; N = 2048;
    n0 = (r & 63) * 32; k0 = (r >> 6) * 32; outRowOff = 0;
  } else {
    int r = id - 6144;
    W = Wc; WT = WcT; K = 2048; N = 1024;
    n0 = (r & 31) * 32; k0 = (r >> 5) * 32; outRowOff = 0;
  }
  int tx = threadIdx.x & 31, ty = threadIdx.x >> 5;
#pragma unroll
  for (int p = 0; p < 4; ++p)
    tile[ty + 8 * p][tx] = W[(size_t)(k0 + ty + 8 * p) * N + n0 + tx];
  __syncthreads();
#pragma unroll
  for (int p = 0; p < 4; ++p)
    WT[(size_t)(outRowOff + n0 + ty + 8 * p) * K + k0 + tx] = f2bf(tile[tx][ty + 8 * p]);
}

// ---------------- GEMM: C[M][N] = A[M][K] @ BT[N][K]^T + bias ----------------
// m97 geometry: 128x128 tile, BK=64, 4 waves, global_load_lds width 16.
// Fused q|k|v (N=2048): rows<4096 -> bf16 q1q2[M][2048];
//   rows 4096..8191 -> kT[((b*2+stream)*16+h)][t][d] at Cv+8388608;
//   rows >=8192 -> vvT ((b*2048+col)*2048+t) at Cv+16777216.
// Bias read directly from the four 1024-f32 inputs + bv (block-uniform select).
#define BM 128
#define BN 128
#define BK 64

__global__ __launch_bounds__(256) void gemm_proj(const u16* __restrict__ A,
                                                 const u16* __restrict__ BT,
                                                 const float* __restrict__ bq1,
                                                 const float* __restrict__ bq2,
                                                 const float* __restrict__ bk1,
                                                 const float* __restrict__ bk2,
                                                 const float* __restrict__ bv,
                                                 void* __restrict__ Cv,
                                                 int M, int N, int K) {
  __shared__ __align__(16) u16 As[BM * BK];
  __shared__ __align__(16) u16 Bs[BN * BK];
  int t = threadIdx.x;
  int w = t >> 6, l = t & 63;
  int g = l >> 4, c16 = l & 15;
  int wr = w >> 1, wc = w & 1;
  size_t gm = (size_t)blockIdx.y * BM, gn = (size_t)blockIdx.x * BN;
  const float* pA;
  const float* pB;
  if (gm >= 8192) {
    BT += (size_t)4096 * 1024;  // WvT after Wk12T
    pA = bv; pB = bv + 1024;
  } else if (gm >= 4096) {
    BT += (size_t)2048 * 1024;  // Wk12T after Wq12T
    pA = bk1; pB = bk2;
  } else {
    pA = bq1; pB = bq2;
  }
  const float* bp = (gn < 1024) ? pA : (pB - 1024);  // block-uniform

  f32x4 acc[4][4] = {};

  int srow = l >> 3;       // 0..7 (8 lanes per row, 8 elems each)
  int scol = (l & 7) * 8;  // 0..56
  const u16* Ag = A + (gm + w * 32 + srow) * (size_t)K + scol;
  const u16* Bg = BT + (gn + w * 32 + srow) * (size_t)K + scol;

  for (int kt = 0; kt < K; kt += BK) {
    __syncthreads();
#pragma unroll
    for (int c = 0; c < 4; ++c) {
      __builtin_amdgcn_global_load_lds(
          (const __attribute__((address_space(1))) void*)(Ag + (size_t)(c * 8) * K + kt),
          (__attribute__((address_space(3))) void*)&As[(w * 32 + c * 8) * BK], 16, 0, 0);
      __builtin_amdgcn_global_load_lds(
          (const __attribute__((address_space(1))) void*)(Bg + (size_t)(c * 8) * K + kt),
          (__attribute__((address_space(3))) void*)&Bs[(w * 32 + c * 8) * BK], 16, 0, 0);
    }
    __syncthreads();
#pragma unroll
    for (int kk = 0; kk < 2; ++kk) {
      short8 af[4], bf[4];
#pragma unroll
      for (int m = 0; m < 4; ++m)
        af[m] = *reinterpret_cast<const short8*>(
            &As[(wr * 64 + m * 16 + c16) * BK + kk * 32 + g * 8]);
#pragma unroll
      for (int n = 0; n < 4; ++n)
        bf[n] = *reinterpret_cast<const short8*>(
            &Bs[(wc * 64 + n * 16 + c16) * BK + kk * 32 + g * 8]);
#pragma unroll
      for (int m = 0; m < 4; ++m)
#pragma unroll
        for (int n = 0; n < 4; ++n)
          acc[m][n] = mfma16(af[m], bf[n], acc[m][n]);
    }
  }

#pragma unroll
  for (int m = 0; m < 4; ++m)
#pragma unroll
    for (int n = 0; n < 4; ++n) {
      int row0 = (int)gm + wr * 64 + m * 16 + g * 4;
      int col = (int)gn + wc * 64 + n * 16 + c16;
      float bz = bp[col];
      u16* C = (u16*)Cv;
      if (row0 < 4096) {
#pragma unroll
        for (int r = 0; r < 4; ++r)
          C[(size_t)(row0 + r) * N + col] = f2bf(acc[m][n][r] + bz);
      } else if (row0 < 8192) {
        int t0 = row0 - 4096;
        int bb = t0 >> 11, tt = t0 & 2047;
        int str = col >> 10, hh = (col >> 6) & 15, dd = col & 63;
        u16* KT = C + 8388608;
        size_t base = (((size_t)(bb * 2 + str) * 16 + hh) * 2048 + tt) * (size_t)64 + dd;
#pragma unroll
        for (int r = 0; r < 4; ++r) KT[base + (size_t)r * 64] = f2bf(acc[m][n][r] + bz);
      } else {
        int t0 = row0 - 8192;
        int bb = t0 >> 11, tt = t0 & 2047;
        u16* VT = C + 16777216;
        union { u16 u[4]; uint2 v; } pk;
#pragma unroll
        for (int r = 0; r < 4; ++r) pk.u[r] = f2bf(acc[m][n][r] + bz);
        *reinterpret_cast<uint2*>(&VT[((size_t)(bb * 2048 + col)) * 2048 + tt]) = pk.v;
      }
    }
}

// -------- final GEMM: 64x64 tile (1024 blocks = 4/CU, 16 waves/CU), f32 out ----
// block 256 = 4 waves; wave w owns rows [w*16, +16) x 64 cols; acc[1][4].
#define BMf 64
#define BNf 64
__global__ __launch_bounds__(256) void gemm_fin(const u16* __restrict__ A,
                                                const u16* __restrict__ BT,
                                                const float* __restrict__ bias,
                                                float* __restrict__ C,
                                                int M, int N, int K) {
  __shared__ __align__(16) u16 As[BMf * BK];
  __shared__ __align__(16) u16 Bs[BNf * BK];
  int t = threadIdx.x;
  int w = t >> 6, l = t & 63;
  int g = l >> 4, c16 = l & 15;
  size_t gm = (size_t)blockIdx.y * BMf, gn = (size_t)blockIdx.x * BNf;

  f32x4 acc[4] = {};

  int srow = l >> 3;       // 0..7
  int scol = (l & 7) * 8;  // 0..56
  const u16* Ag = A + (gm + w * 16 + srow) * (size_t)K + scol;
  const u16* Bg = BT + (gn + w * 16 + srow) * (size_t)K + scol;

  for (int kt = 0; kt < K; kt += BK) {
    __syncthreads();
#pragma unroll
    for (int c = 0; c < 2; ++c) {
      __builtin_amdgcn_global_load_lds(
          (const __attribute__((address_space(1))) void*)(Ag + (size_t)(c * 8) * K + kt),
          (__attribute__((address_space(3))) void*)&As[(w * 16 + c * 8) * BK], 16, 0, 0);
      __builtin_amdgcn_global_load_lds(
          (const __attribute__((address_space(1))) void*)(Bg + (size_t)(c * 8) * K + kt),
          (__attribute__((address_space(3))) void*)&Bs[(w * 16 + c * 8) * BK], 16, 0, 0);
    }
    __syncthreads();
#pragma unroll
    for (int kk = 0; kk < 2; ++kk) {
      short8 af = *reinterpret_cast<const short8*>(
          &As[(w * 16 + c16) * BK + kk * 32 + g * 8]);
#pragma unroll
      for (int n = 0; n < 4; ++n) {
        short8 bf = *reinterpret_cast<const short8*>(
            &Bs[(n * 16 + c16) * BK + kk * 32 + g * 8]);
        acc[n] = mfma16(af, bf, acc[n]);
      }
    }
  }

#pragma unroll
  for (int n = 0; n < 4; ++n) {
    int row0 = (int)gm + w * 16 + g * 4;
    int col = (int)gn + n * 16 + c16;
    float bz = bias[col];
#pragma unroll
    for (int r = 0; r < 4; ++r)
      C[(size_t)(row0 + r) * N + col] = acc[n][r] + bz;
  }
}

// ---------------- differential flash attention + fused LN (32x32 swapped) ----
// grid 1024 (1D, XCD-swizzled), block 256 = 4 waves = 2 pairs.
// Pair p covers q-rows [xblk*64 + p*32, +32); wave stream s handles stream s+1.
// 64-key staged tiles, 2-barrier R8/R12-proven staging, COALESCED sources:
// K from kT (contiguous 8KB/stream/tile), V along t (64B/thread contiguous).
#define KROW 72   // K/V LDS row: 64 elems + 8 pad (144B)
#define YROW 72
__global__ __launch_bounds__(256, 3) void diffattn(
    const u16* __restrict__ q1q2, const u16* __restrict__ kT,
    const u16* __restrict__ vvT, const int* __restrict__ mask,
    const float* __restrict__ lq1, const float* __restrict__ lk1,
    const float* __restrict__ lq2, const float* __restrict__ lk2,
    const float* __restrict__ lnw, const float* __restrict__ lnb,
    u16* __restrict__ yout) {
  // Ks [128 rows = stream*64+key][KROW] = 9216 ; Vs [128 d-rows][KROW] = 9216
  __shared__ __align__(16) u16 smem[18432];
  u16* Ksm = smem;
  u16* Vsm = smem + 9216;
  u16* Ysm = smem;  // epilogue overlay

  int tid = threadIdx.x;
  int w = tid >> 6, l = tid & 63;
  int q = l & 31, hi = l >> 5;
  int pair = w >> 1, stream = w & 1;

  // XCD swizzle: same-(b,h) q-blocks land on one XCD -> K/V L2-local
  int id = blockIdx.x;            // 0..1023
  int j = id & 7, rest = id >> 3;
  int xblk = rest & 31, ygrp = rest >> 5;
  int bh = ygrp * 8 + j;
  int b = bh >> 4, h = bh & 15;
  int qr0 = xblk * 64 + pair * 32;

  // lambda
  float lm1 = lq1[h * 64 + l] * lk1[h * 64 + l];
  float lm2 = lq2[h * 64 + l] * lk2[h * 64 + l];
#pragma unroll
  for (int o = 32; o; o >>= 1) {
    lm1 += __shfl_xor(lm1, o);
    lm2 += __shfl_xor(lm2, o);
  }
  float lam = __expf(lm1) - __expf(lm2) + LAMBDA_INIT;

  int soff = stream * 1024;
  const u16* qrow = q1q2 + (size_t)(b * T_SEQ + qr0 + q) * 2048 + h * 64 + soff + hi * 8;
  short8 qf[4];
#pragma unroll
  for (int c = 0; c < 4; ++c) qf[c] = ld8(qrow + c * 16);

  // softmax in log2 domain; mask folds into scale (0 -> uniform softmax)
  float scale = (mask[b * T_SEQ + qr0 + q] == 0) ? 0.f : (SM_SCALE * LOG2E);

  float M = -INFINITY, Lp = 0.f;
  f32x16 acc[4] = {};

  // ---- coalesced staging (256 threads, 8 ld8/thread, all contiguous) ----
  // K: per stream, thread t covers 16 contiguous elems at offset t*16 of the
  //    64x64 kT tile (8KB contiguous per tile).
  int koff = tid * 16;                 // 0..4095
  int krw = koff >> 6, kcl = koff & 63;
  const u16* srcK0 = kT + (((size_t)(b * 2 + 0) * 16 + h) * 2048) * 64 + koff;
  const u16* srcK1 = kT + (((size_t)(b * 2 + 1) * 16 + h) * 2048) * 64 + koff;
  u16* dstK0 = &Ksm[krw * KROW + kcl];
  u16* dstK1 = &Ksm[(64 + krw) * KROW + kcl];
  // V: thread t covers 32 contiguous t-elems of d-row (t>>1) at col (t&1)*32.
  int vd0 = tid >> 1, tcol = (tid & 1) * 32;
  const u16* srcV = vvT + ((size_t)(b * 16 + h) * 128 + vd0) * 2048 + tcol;
  u16* dstV = &Vsm[vd0 * KROW + tcol];

  short8 kpa0, kpa1, kpb0, kpb1, vp0, vp1, vp2, vp3;
  kpa0 = ld8(srcK0); kpa1 = ld8(srcK0 + 8);
  kpb0 = ld8(srcK1); kpb1 = ld8(srcK1 + 8);
  vp0 = ld8(srcV); vp1 = ld8(srcV + 8); vp2 = ld8(srcV + 16); vp3 = ld8(srcV + 24);

  for (int kt = 0; kt < T_SEQ; kt += 64) {
    __syncthreads();  // previous tile's reads complete
    st8(dstK0, kpa0); st8(dstK0 + 8, kpa1);
    st8(dstK1, kpb0); st8(dstK1 + 8, kpb1);
    st8(dstV, vp0); st8(dstV + 8, vp1); st8(dstV + 16, vp2); st8(dstV + 24, vp3);
    __syncthreads();  // tile staged
    if (kt + 64 < T_SEQ) {  // prefetch next tile (consumed NEXT iter)
      size_t ko = (size_t)(kt + 64) * 64;
      kpa0 = ld8(srcK0 + ko); kpa1 = ld8(srcK0 + ko + 8);
      kpb0 = ld8(srcK1 + ko); kpb1 = ld8(srcK1 + ko + 8);
      const u16* nv = srcV + kt + 64;
      vp0 = ld8(nv); vp1 = ld8(nv + 8); vp2 = ld8(nv + 16); vp3 = ld8(nv + 24);
    }

#pragma unroll
    for (int st = 0; st < 2; ++st) {
      const u16* kbase = &Ksm[(stream * 64 + st * 32 + q) * KROW + hi * 8];
      short8 kf[4];
#pragma unroll
      for (int c = 0; c < 4; ++c) kf[c] = ld8(kbase + c * 16);

      f32x16 s = {};
#pragma unroll
      for (int c = 0; c < 4; ++c) s = mfma32(kf[c], qf[c], s);

      // tile max: max3-fusable tree + cross-half
      float m0 = fmaxf(fmaxf(s[0], s[1]), s[2]);
      float m1 = fmaxf(fmaxf(s[3], s[4]), s[5]);
      float m2 = fmaxf(fmaxf(s[6], s[7]), s[8]);
      float m3 = fmaxf(fmaxf(s[9], s[10]), s[11]);
      float m4 = fmaxf(fmaxf(s[12], s[13]), s[14]);
      float ma = fmaxf(fmaxf(m0, m1), m2);
      float mb = fmaxf(fmaxf(m3, m4), s[15]);
      float rm = fmaxf(ma, mb);
      rm = fmaxf(rm, __shfl_xor(rm, 32));
      float tm = rm * scale;

      // defer-max (log2 units: 11.5 ~ e^8); M synced across halves
      if (!__all(tm - M <= 11.5f)) {
        float Mn = fmaxf(M, tm);
        float a = exp2f(M - Mn);
        Lp *= a;
#pragma unroll
        for (int d = 0; d < 4; ++d) acc[d] *= a;
        M = Mn;
      }

      // p = exp2(s*scale - M); lane-local partial sum (combined once at end)
      float p[16];
#pragma unroll
      for (int r = 0; r < 16; ++r) p[r] = exp2f(__builtin_fmaf(s[r], scale, -M));
      float s8[8], s4[4];
#pragma unroll
      for (int i = 0; i < 8; ++i) s8[i] = p[i] + p[i + 8];
#pragma unroll
      for (int i = 0; i < 4; ++i) s4[i] = s8[i] + s8[i + 4];
      Lp += (s4[0] + s4[1]) + (s4[2] + s4[3]);

      // P^T B-frags in-register
      uint32_t a1 = cvtpk(p[0], p[1]), a2 = cvtpk(p[2], p[3]);
      uint32_t b1 = cvtpk(p[4], p[5]), b2 = cvtpk(p[6], p[7]);
      uint32_t c1 = cvtpk(p[8], p[9]), c2 = cvtpk(p[10], p[11]);
      uint32_t d1 = cvtpk(p[12], p[13]), d2 = cvtpk(p[14], p[15]);
      uint32_t sa1 = (uint32_t)__shfl_xor((int)a1, 32), sa2 = (uint32_t)__shfl_xor((int)a2, 32);
      uint32_t sb1 = (uint32_t)__shfl_xor((int)b1, 32), sb2 = (uint32_t)__shfl_xor((int)b2, 32);
      uint32_t sc1 = (uint32_t)__shfl_xor((int)c1, 32), sc2 = (uint32_t)__shfl_xor((int)c2, 32);
      uint32_t sd1 = (uint32_t)__shfl_xor((int)d1, 32), sd2 = (uint32_t)__shfl_xor((int)d2, 32);
      union { uint32_t u[4]; short8 s8v; } pu0, pu1;
      pu0.u[0] = hi ? sb1 : a1;  pu0.u[1] = hi ? sb2 : a2;
      pu0.u[2] = hi ? b1 : sa1;  pu0.u[3] = hi ? b2 : sa2;
      pu1.u[0] = hi ? sd1 : c1;  pu1.u[1] = hi ? sd2 : c2;
      pu1.u[2] = hi ? d1 : sc1;  pu1.u[3] = hi ? d2 : sc2;
      short8 pf0 = pu0.s8v, pf1 = pu1.s8v;

#pragma unroll
      for (int d = 0; d < 4; ++d) {
        const u16* vb0 = &Vsm[(d * 32 + q) * KROW + st * 32 + hi * 8];
        short8 vf0 = ld8(vb0);
        short8 vf1 = ld8(vb0 + 16);
        acc[d] = mfma32(vf0, pf0, acc[d]);
        acc[d] = mfma32(vf1, pf1, acc[d]);
      }
    }
  }

  float L = Lp + __shfl_xor(Lp, 32);
  float inv = 1.f / L;
  __syncthreads();  // staging dead -> Ysm overlay safe
  if (stream == 1) {
    u16* yrow = &Ysm[(pair * 64 + l) * YROW];
#pragma unroll
    for (int d = 0; d < 4; ++d) {
      union { uint32_t u[8]; short8 v[2]; } pk;
#pragma unroll
      for (int i = 0; i < 8; ++i)
        pk.u[i] = cvtpk(acc[d][2 * i] * inv, acc[d][2 * i + 1] * inv);
      st8(yrow + d * 16, pk.v[0]);
      st8(yrow + d * 16 + 8, pk.v[1]);
    }
  }
  __syncthreads();
  if (stream == 0) {
    const u16* yrow = &Ysm[(pair * 64 + l) * YROW];
    float y[4][16];
#pragma unroll
    for (int d = 0; d < 4; ++d) {
      short8 y2a = ld8(yrow + d * 16);
      short8 y2b = ld8(yrow + d * 16 + 8);
#pragma unroll
      for (int i = 0; i < 8; ++i) {
        y[d][i] = acc[d][i] * inv - lam * b2f((u16)y2a[i]);
        y[d][8 + i] = acc[d][8 + i] * inv - lam * b2f((u16)y2b[i]);
      }
    }
    float sm = 0.f;
#pragma unroll
    for (int d = 0; d < 4; ++d)
#pragma unroll
      for (int r = 0; r < 16; ++r) sm += y[d][r];
    sm += __shfl_xor(sm, 32);
    float u = sm * (1.f / 128.f);
    float var = 0.f;
#pragma unroll
    for (int d = 0; d < 4; ++d)
#pragma unroll
      for (int r = 0; r < 16; ++r) { float dd = y[d][r] - u; var += dd * dd; }
    var += __shfl_xor(var, 32);
    float rstd = rsqrtf(var * (1.f / 128.f) + 1e-12f);

    size_t orow = (size_t)(b * T_SEQ + qr0 + q) * 2048 + h * 128;
#pragma unroll
    for (int d = 0; d < 4; ++d)
#pragma unroll
      for (int rr = 0; rr < 4; ++rr) {
        int base = d * 32 + 8 * rr + 4 * hi;
        union { u16 u[4]; uint2 v; } o;
#pragma unroll
        for (int i = 0; i < 4; ++i) {
          float yv = (lnw[base + i] * ((y[d][rr * 4 + i] - u) * rstd) + lnb[base + i]) *
                     ONE_MINUS_LI;
          o.u[i] = f2bf(yv);
        }
        *reinterpret_cast<uint2*>(&yout[orow + base]) = o.v;
      }
  }
}

// ---------------- host ----------------
extern "C" void kernel_launch(void* const* d_in, const int* in_sizes, int n_in,
                              void* d_out, int out_size, void* d_ws, size_t ws_size,
                              hipStream_t stream) {
  (void)in_sizes; (void)n_in; (void)out_size; (void)ws_size;
  const float* q   = (const float*)d_in[0];
  const float* k   = (const float*)d_in[1];
  const float* v   = (const float*)d_in[2];
  const int* maskp = (const int*)d_in[3];
  const float* Wq1 = (const float*)d_in[4];
  const float* bq1 = (const float*)d_in[5];
  const float* Wq2 = (const float*)d_in[6];
  const float* bq2 = (const float*)d_in[7];
  const float* Wk1 = (const float*)d_in[8];
  const float* bk1 = (const float*)d_in[9];
  const float* Wk2 = (const float*)d_in[10];
  const float* bk2 = (const float*)d_in[11];
  const float* Wv  = (const float*)d_in[12];
  const float* bv  = (const float*)d_in[13];
  const float* Wc  = (const float*)d_in[14];
  const float* bc  = (const float*)d_in[15];
  const float* lnw = (const float*)d_in[16];
  const float* lnb = (const float*)d_in[17];
  const float* lq1 = (const float*)d_in[18];
  const float* lk1 = (const float*)d_in[19];
  const float* lq2 = (const float*)d_in[20];
  const float* lk2 = (const float*)d_in[21];

  char* ws = (char*)d_ws;
  u16* qb     = (u16*)(ws + 0);          // qb|kb|vb contiguous [12288][1024]
  u16* Wq12T  = (u16*)(ws + 25165824);   // Wq12T|Wk12T|WvT contiguous [6144][1024]
  u16* WvT    = (u16*)(ws + 33554432);
  u16* WcT    = (u16*)(ws + 37748736);
  u16* q1q2   = (u16*)(ws + 41959424);   // q1q2|kT|vvT contiguous
  u16* kT     = (u16*)(ws + 58736640);
  u16* vvT    = (u16*)(ws + 75513856);
  u16* yb     = (u16*)(ws + 0);  // alias qb+kb (16MB; both dead before attention)

  const int NELEM = 2 * T_SEQ * 1024;  // 4,194,304

  prep<<<20480, 256, 0, stream>>>(q, k, v, qb, NELEM,
                                  Wq1, Wq2, Wk1, Wk2, Wv, Wc, Wq12T, WvT, WcT);

  // ONE projection GEMM: M=12288 over qb|kb|vb; epilogues q1q2 / kT / vvT
  gemm_proj<<<dim3(16, 96), 256, 0, stream>>>(qb, Wq12T, bq1, bq2, bk1, bk2, bv,
                                              q1q2, 12288, 2048, 1024);

  diffattn<<<1024, 256, 0, stream>>>(q1q2, kT, vvT, maskp,
                                     lq1, lk1, lq2, lk2, lnw, lnb, yb);

  // final GEMM: 64x64 tile, 1024 blocks = 4/CU (was grid-limited at 2/CU)
  gemm_fin<<<dim3(16, 64), 256, 0, stream>>>(yb, WcT, bc, (float*)d_out,
                                             4096, 1024, 2048);
}

// Round 24
// 302.364 us; speedup vs baseline: 1.0033x; 1.0033x over previous
//
#include <hip/hip_runtime.h>
#include <hip/hip_bf16.h>
#include <stdint.h>

// MultiHeadDiffAttention — R24 = exact revert to R22 (session best, 301.7us).
// R23's two launch-shape changes were neutral-to-negative (smaller gemm_fin
// tile halved staging width per iter; prep merge saved nothing) -> reverted.
// Pipeline at validated-structure optimum: diffattn 182us (regalloc-frozen),
// gemm_proj at m97 ceiling, prep at HBM floor, gemm_fin best at 128x64/2-per-CU.
// B=2, T=2048, C=1024, H=16, HS=64.

#define T_SEQ 2048

typedef unsigned short u16;
typedef __attribute__((ext_vector_type(8))) short short8;
typedef __attribute__((ext_vector_type(4))) float f32x4;
typedef __attribute__((ext_vector_type(16))) float f32x16;

#define LAMBDA_INIT 0.35550906759096926f
#define ONE_MINUS_LI 0.6444909324090307f
#define SM_SCALE 0.125f
#define LOG2E 1.44269504f

__device__ __forceinline__ u16 f2bf(float f) {
  uint32_t u = __float_as_uint(f);
  return (u16)((u + 0x7FFFu + ((u >> 16) & 1u)) >> 16);
}
__device__ __forceinline__ float b2f(u16 u) {
  return __uint_as_float(((uint32_t)u) << 16);
}
__device__ __forceinline__ short8 ld8(const u16* p) {
  return *reinterpret_cast<const short8*>(p);
}
__device__ __forceinline__ void st8(u16* p, short8 v) {
  *reinterpret_cast<short8*>(p) = v;
}
__device__ __forceinline__ f32x4 mfma16(short8 a, short8 b, f32x4 c) {
  return __builtin_amdgcn_mfma_f32_16x16x32_bf16(a, b, c, 0, 0, 0);
}
__device__ __forceinline__ f32x16 mfma32(short8 a, short8 b, f32x16 c) {
  return __builtin_amdgcn_mfma_f32_32x32x16_bf16(a, b, c, 0, 0, 0);
}
__device__ __forceinline__ uint32_t cvtpk(float lo, float hi_) {
  uint32_t r;
  asm("v_cvt_pk_bf16_f32 %0, %1, %2" : "=v"(r) : "v"(lo), "v"(hi_));
  return r;
}

// ------------- merged elementwise f32 -> bf16 (q,k,v in one launch) -------------
__global__ __launch_bounds__(256) void cvt3_bf16(const float* __restrict__ q,
                                                 const float* __restrict__ k,
                                                 const float* __restrict__ v,
                                                 u16* __restrict__ out, int n) {
  int i = (blockIdx.x * 256 + threadIdx.x) * 4;  // over 3n elems
  const float* src;
  int j = i;
  if (i < n) src = q;
  else if (i < 2 * n) { src = k; j = i - n; }
  else { src = v; j = i - 2 * n; }
  float4 f = *reinterpret_cast<const float4*>(src + j);
  union { u16 u[4]; uint2 v2; } pk;
  pk.u[0] = f2bf(f.x); pk.u[1] = f2bf(f.y); pk.u[2] = f2bf(f.z); pk.u[3] = f2bf(f.w);
  *reinterpret_cast<uint2*>(out + i) = pk.v2;
}

// ----- tcvt6: all six weight transposes in ONE 1D launch (8192 blocks) -----
// id<4096: four 1024x1024 (Wq1,Wq2,Wk1,Wk2 -> WqkT rows z*1024)
// id<6144: Wv 1024x2048 -> WvT ; else: Wc 2048x1024 -> WcT
__global__ __launch_bounds__(256) void tcvt6(const float* __restrict__ W0,
                                             const float* __restrict__ W1,
                                             const float* __restrict__ W2,
                                             const float* __restrict__ W3,
                                             const float* __restrict__ Wv,
                                             const float* __restrict__ Wc,
                                             u16* __restrict__ WqkT,
                                             u16* __restrict__ WvT,
                                             u16* __restrict__ WcT) {
  __shared__ float tile[32][33];
  int id = blockIdx.x;
  const float* W; u16* WT; int K, N, n0, k0, outRowOff;
  if (id < 4096) {
    int z = id >> 10, r = id & 1023;
    W = (z == 0) ? W0 : (z == 1) ? W1 : (z == 2) ? W2 : W3;
    WT = WqkT; K = 1024; N = 1024;
    n0 = (r & 31) * 32; k0 = (r >> 5) * 32; outRowOff = z * 1024;
  } else if (id < 6144) {
    int r = id - 4096;
    W = Wv; WT = WvT; K = 1024; N = 2048;
    n0 = (r & 63) * 32; k0 = (r >> 6) * 32; outRowOff = 0;
  } else {
    int r = id - 6144;
    W = Wc; WT = WcT; K = 2048; N = 1024;
    n0 = (r & 31) * 32; k0 = (r >> 5) * 32; outRowOff = 0;
  }
  int tx = threadIdx.x & 31, ty = threadIdx.x >> 5;
#pragma unroll
  for (int p = 0; p < 4; ++p)
    tile[ty + 8 * p][tx] = W[(size_t)(k0 + ty + 8 * p) * N + n0 + tx];
  __syncthreads();
#pragma unroll
  for (int p = 0; p < 4; ++p)
    WT[(size_t)(outRowOff + n0 + ty + 8 * p) * K + k0 + tx] = f2bf(tile[tx][ty + 8 * p]);
}

// ---------------- GEMM: C[M][N] = A[M][K] @ BT[N][K]^T + bias ----------------
// m97 geometry: 128x128 tile, BK=64, 4 waves, global_load_lds width 16.
// Fused q|k|v (N=2048): rows<4096 -> bf16 q1q2[M][2048];
//   rows 4096..8191 -> kT[((b*2+stream)*16+h)][t][d] at Cv+8388608;
//   rows >=8192 -> vvT ((b*2048+col)*2048+t) at Cv+16777216.
// Bias read directly from the four 1024-f32 inputs + bv (block-uniform select:
// BN=128 blocks never straddle the 1024 column boundary).
#define BM 128
#define BN 128
#define BK 64

__global__ __launch_bounds__(256) void gemm_proj(const u16* __restrict__ A,
                                                 const u16* __restrict__ BT,
                                                 const float* __restrict__ bq1,
                                                 const float* __restrict__ bq2,
                                                 const float* __restrict__ bk1,
                                                 const float* __restrict__ bk2,
                                                 const float* __restrict__ bv,
                                                 void* __restrict__ Cv,
                                                 int M, int N, int K) {
  __shared__ __align__(16) u16 As[BM * BK];
  __shared__ __align__(16) u16 Bs[BN * BK];
  int t = threadIdx.x;
  int w = t >> 6, l = t & 63;
  int g = l >> 4, c16 = l & 15;
  int wr = w >> 1, wc = w & 1;
  size_t gm = (size_t)blockIdx.y * BM, gn = (size_t)blockIdx.x * BN;
  const float* pA;
  const float* pB;
  if (gm >= 8192) {
    BT += (size_t)4096 * 1024;  // WvT after Wk12T
    pA = bv; pB = bv + 1024;
  } else if (gm >= 4096) {
    BT += (size_t)2048 * 1024;  // Wk12T after Wq12T
    pA = bk1; pB = bk2;
  } else {
    pA = bq1; pB = bq2;
  }
  const float* bp = (gn < 1024) ? pA : (pB - 1024);  // block-uniform

  f32x4 acc[4][4] = {};

  int srow = l >> 3;       // 0..7 (8 lanes per row, 8 elems each)
  int scol = (l & 7) * 8;  // 0..56
  const u16* Ag = A + (gm + w * 32 + srow) * (size_t)K + scol;
  const u16* Bg = BT + (gn + w * 32 + srow) * (size_t)K + scol;

  for (int kt = 0; kt < K; kt += BK) {
    __syncthreads();
#pragma unroll
    for (int c = 0; c < 4; ++c) {
      __builtin_amdgcn_global_load_lds(
          (const __attribute__((address_space(1))) void*)(Ag + (size_t)(c * 8) * K + kt),
          (__attribute__((address_space(3))) void*)&As[(w * 32 + c * 8) * BK], 16, 0, 0);
      __builtin_amdgcn_global_load_lds(
          (const __attribute__((address_space(1))) void*)(Bg + (size_t)(c * 8) * K + kt),
          (__attribute__((address_space(3))) void*)&Bs[(w * 32 + c * 8) * BK], 16, 0, 0);
    }
    __syncthreads();
#pragma unroll
    for (int kk = 0; kk < 2; ++kk) {
      short8 af[4], bf[4];
#pragma unroll
      for (int m = 0; m < 4; ++m)
        af[m] = *reinterpret_cast<const short8*>(
            &As[(wr * 64 + m * 16 + c16) * BK + kk * 32 + g * 8]);
#pragma unroll
      for (int n = 0; n < 4; ++n)
        bf[n] = *reinterpret_cast<const short8*>(
            &Bs[(wc * 64 + n * 16 + c16) * BK + kk * 32 + g * 8]);
#pragma unroll
      for (int m = 0; m < 4; ++m)
#pragma unroll
        for (int n = 0; n < 4; ++n)
          acc[m][n] = mfma16(af[m], bf[n], acc[m][n]);
    }
  }

#pragma unroll
  for (int m = 0; m < 4; ++m)
#pragma unroll
    for (int n = 0; n < 4; ++n) {
      int row0 = (int)gm + wr * 64 + m * 16 + g * 4;
      int col = (int)gn + wc * 64 + n * 16 + c16;
      float bz = bp[col];
      u16* C = (u16*)Cv;
      if (row0 < 4096) {
#pragma unroll
        for (int r = 0; r < 4; ++r)
          C[(size_t)(row0 + r) * N + col] = f2bf(acc[m][n][r] + bz);
      } else if (row0 < 8192) {
        int t0 = row0 - 4096;
        int bb = t0 >> 11, tt = t0 & 2047;
        int str = col >> 10, hh = (col >> 6) & 15, dd = col & 63;
        u16* KT = C + 8388608;
        size_t base = (((size_t)(bb * 2 + str) * 16 + hh) * 2048 + tt) * (size_t)64 + dd;
#pragma unroll
        for (int r = 0; r < 4; ++r) KT[base + (size_t)r * 64] = f2bf(acc[m][n][r] + bz);
      } else {
        int t0 = row0 - 8192;
        int bb = t0 >> 11, tt = t0 & 2047;
        u16* VT = C + 16777216;
        union { u16 u[4]; uint2 v; } pk;
#pragma unroll
        for (int r = 0; r < 4; ++r) pk.u[r] = f2bf(acc[m][n][r] + bz);
        *reinterpret_cast<uint2*>(&VT[((size_t)(bb * 2048 + col)) * 2048 + tt]) = pk.v;
      }
    }
}

// -------- final GEMM: 128x64 tile (512 blocks = 2/CU), f32 output --------
#define BMf 128
#define BNf 64
__global__ __launch_bounds__(256) void gemm_fin(const u16* __restrict__ A,
                                                const u16* __restrict__ BT,
                                                const float* __restrict__ bias,
                                                float* __restrict__ C,
                                                int M, int N, int K) {
  __shared__ __align__(16) u16 As[BMf * BK];
  __shared__ __align__(16) u16 Bs[BNf * BK];
  int t = threadIdx.x;
  int w = t >> 6, l = t & 63;
  int g = l >> 4, c16 = l & 15;
  size_t gm = (size_t)blockIdx.y * BMf, gn = (size_t)blockIdx.x * BNf;

  f32x4 acc[2][4] = {};

  int srow = l >> 3;       // 0..7
  int scol = (l & 7) * 8;  // 0..56
  const u16* Ag = A + (gm + w * 32 + srow) * (size_t)K + scol;
  const u16* Bg = BT + (gn + w * 16 + srow) * (size_t)K + scol;

  for (int kt = 0; kt < K; kt += BK) {
    __syncthreads();
#pragma unroll
    for (int c = 0; c < 4; ++c)
      __builtin_amdgcn_global_load_lds(
          (const __attribute__((address_space(1))) void*)(Ag + (size_t)(c * 8) * K + kt),
          (__attribute__((address_space(3))) void*)&As[(w * 32 + c * 8) * BK], 16, 0, 0);
#pragma unroll
    for (int c = 0; c < 2; ++c)
      __builtin_amdgcn_global_load_lds(
          (const __attribute__((address_space(1))) void*)(Bg + (size_t)(c * 8) * K + kt),
          (__attribute__((address_space(3))) void*)&Bs[(w * 16 + c * 8) * BK], 16, 0, 0);
    __syncthreads();
#pragma unroll
    for (int kk = 0; kk < 2; ++kk) {
      short8 af[2], bf[4];
#pragma unroll
      for (int m = 0; m < 2; ++m)
        af[m] = *reinterpret_cast<const short8*>(
            &As[(w * 32 + m * 16 + c16) * BK + kk * 32 + g * 8]);
#pragma unroll
      for (int n = 0; n < 4; ++n)
        bf[n] = *reinterpret_cast<const short8*>(
            &Bs[(n * 16 + c16) * BK + kk * 32 + g * 8]);
#pragma unroll
      for (int m = 0; m < 2; ++m)
#pragma unroll
        for (int n = 0; n < 4; ++n)
          acc[m][n] = mfma16(af[m], bf[n], acc[m][n]);
    }
  }

#pragma unroll
  for (int m = 0; m < 2; ++m)
#pragma unroll
    for (int n = 0; n < 4; ++n) {
      int row0 = (int)gm + w * 32 + m * 16 + g * 4;
      int col = (int)gn + n * 16 + c16;
      float bz = bias[col];
#pragma unroll
      for (int r = 0; r < 4; ++r)
        C[(size_t)(row0 + r) * N + col] = acc[m][n][r] + bz;
    }
}

// ---------------- differential flash attention + fused LN (32x32 swapped) ----
// grid 1024 (1D, XCD-swizzled), block 256 = 4 waves = 2 pairs.
// Pair p covers q-rows [xblk*64 + p*32, +32); wave stream s handles stream s+1.
// 64-key staged tiles, 2-barrier R8/R12-proven staging, COALESCED sources:
// K from kT (contiguous 8KB/stream/tile), V along t (64B/thread contiguous).
#define KROW 72   // K/V LDS row: 64 elems + 8 pad (144B)
#define YROW 72
__global__ __launch_bounds__(256, 3) void diffattn(
    const u16* __restrict__ q1q2, const u16* __restrict__ kT,
    const u16* __restrict__ vvT, const int* __restrict__ mask,
    const float* __restrict__ lq1, const float* __restrict__ lk1,
    const float* __restrict__ lq2, const float* __restrict__ lk2,
    const float* __restrict__ lnw, const float* __restrict__ lnb,
    u16* __restrict__ yout) {
  // Ks [128 rows = stream*64+key][KROW] = 9216 ; Vs [128 d-rows][KROW] = 9216
  __shared__ __align__(16) u16 smem[18432];
  u16* Ksm = smem;
  u16* Vsm = smem + 9216;
  u16* Ysm = smem;  // epilogue overlay

  int tid = threadIdx.x;
  int w = tid >> 6, l = tid & 63;
  int q = l & 31, hi = l >> 5;
  int pair = w >> 1, stream = w & 1;

  // XCD swizzle: same-(b,h) q-blocks land on one XCD -> K/V L2-local
  int id = blockIdx.x;            // 0..1023
  int j = id & 7, rest = id >> 3;
  int xblk = rest & 31, ygrp = rest >> 5;
  int bh = ygrp * 8 + j;
  int b = bh >> 4, h = bh & 15;
  int qr0 = xblk * 64 + pair * 32;

  // lambda
  float lm1 = lq1[h * 64 + l] * lk1[h * 64 + l];
  float lm2 = lq2[h * 64 + l] * lk2[h * 64 + l];
#pragma unroll
  for (int o = 32; o; o >>= 1) {
    lm1 += __shfl_xor(lm1, o);
    lm2 += __shfl_xor(lm2, o);
  }
  float lam = __expf(lm1) - __expf(lm2) + LAMBDA_INIT;

  int soff = stream * 1024;
  const u16* qrow = q1q2 + (size_t)(b * T_SEQ + qr0 + q) * 2048 + h * 64 + soff + hi * 8;
  short8 qf[4];
#pragma unroll
  for (int c = 0; c < 4; ++c) qf[c] = ld8(qrow + c * 16);

  // softmax in log2 domain; mask folds into scale (0 -> uniform softmax)
  float scale = (mask[b * T_SEQ + qr0 + q] == 0) ? 0.f : (SM_SCALE * LOG2E);

  float M = -INFINITY, Lp = 0.f;
  f32x16 acc[4] = {};

  // ---- coalesced staging (256 threads, 8 ld8/thread, all contiguous) ----
  // K: per stream, thread t covers 16 contiguous elems at offset t*16 of the
  //    64x64 kT tile (8KB contiguous per tile).
  int koff = tid * 16;                 // 0..4095
  int krw = koff >> 6, kcl = koff & 63;
  const u16* srcK0 = kT + (((size_t)(b * 2 + 0) * 16 + h) * 2048) * 64 + koff;
  const u16* srcK1 = kT + (((size_t)(b * 2 + 1) * 16 + h) * 2048) * 64 + koff;
  u16* dstK0 = &Ksm[krw * KROW + kcl];
  u16* dstK1 = &Ksm[(64 + krw) * KROW + kcl];
  // V: thread t covers 32 contiguous t-elems of d-row (t>>1) at col (t&1)*32.
  int vd0 = tid >> 1, tcol = (tid & 1) * 32;
  const u16* srcV = vvT + ((size_t)(b * 16 + h) * 128 + vd0) * 2048 + tcol;
  u16* dstV = &Vsm[vd0 * KROW + tcol];

  short8 kpa0, kpa1, kpb0, kpb1, vp0, vp1, vp2, vp3;
  kpa0 = ld8(srcK0); kpa1 = ld8(srcK0 + 8);
  kpb0 = ld8(srcK1); kpb1 = ld8(srcK1 + 8);
  vp0 = ld8(srcV); vp1 = ld8(srcV + 8); vp2 = ld8(srcV + 16); vp3 = ld8(srcV + 24);

  for (int kt = 0; kt < T_SEQ; kt += 64) {
    __syncthreads();  // previous tile's reads complete
    st8(dstK0, kpa0); st8(dstK0 + 8, kpa1);
    st8(dstK1, kpb0); st8(dstK1 + 8, kpb1);
    st8(dstV, vp0); st8(dstV + 8, vp1); st8(dstV + 16, vp2); st8(dstV + 24, vp3);
    __syncthreads();  // tile staged
    if (kt + 64 < T_SEQ) {  // prefetch next tile (consumed NEXT iter)
      size_t ko = (size_t)(kt + 64) * 64;
      kpa0 = ld8(srcK0 + ko); kpa1 = ld8(srcK0 + ko + 8);
      kpb0 = ld8(srcK1 + ko); kpb1 = ld8(srcK1 + ko + 8);
      const u16* nv = srcV + kt + 64;
      vp0 = ld8(nv); vp1 = ld8(nv + 8); vp2 = ld8(nv + 16); vp3 = ld8(nv + 24);
    }

#pragma unroll
    for (int st = 0; st < 2; ++st) {
      const u16* kbase = &Ksm[(stream * 64 + st * 32 + q) * KROW + hi * 8];
      short8 kf[4];
#pragma unroll
      for (int c = 0; c < 4; ++c) kf[c] = ld8(kbase + c * 16);

      f32x16 s = {};
#pragma unroll
      for (int c = 0; c < 4; ++c) s = mfma32(kf[c], qf[c], s);

      // tile max: max3-fusable tree + cross-half
      float m0 = fmaxf(fmaxf(s[0], s[1]), s[2]);
      float m1 = fmaxf(fmaxf(s[3], s[4]), s[5]);
      float m2 = fmaxf(fmaxf(s[6], s[7]), s[8]);
      float m3 = fmaxf(fmaxf(s[9], s[10]), s[11]);
      float m4 = fmaxf(fmaxf(s[12], s[13]), s[14]);
      float ma = fmaxf(fmaxf(m0, m1), m2);
      float mb = fmaxf(fmaxf(m3, m4), s[15]);
      float rm = fmaxf(ma, mb);
      rm = fmaxf(rm, __shfl_xor(rm, 32));
      float tm = rm * scale;

      // defer-max (log2 units: 11.5 ~ e^8); M synced across halves
      if (!__all(tm - M <= 11.5f)) {
        float Mn = fmaxf(M, tm);
        float a = exp2f(M - Mn);
        Lp *= a;
#pragma unroll
        for (int d = 0; d < 4; ++d) acc[d] *= a;
        M = Mn;
      }

      // p = exp2(s*scale - M); lane-local partial sum (combined once at end)
      float p[16];
#pragma unroll
      for (int r = 0; r < 16; ++r) p[r] = exp2f(__builtin_fmaf(s[r], scale, -M));
      float s8[8], s4[4];
#pragma unroll
      for (int i = 0; i < 8; ++i) s8[i] = p[i] + p[i + 8];
#pragma unroll
      for (int i = 0; i < 4; ++i) s4[i] = s8[i] + s8[i + 4];
      Lp += (s4[0] + s4[1]) + (s4[2] + s4[3]);

      // P^T B-frags in-register
      uint32_t a1 = cvtpk(p[0], p[1]), a2 = cvtpk(p[2], p[3]);
      uint32_t b1 = cvtpk(p[4], p[5]), b2 = cvtpk(p[6], p[7]);
      uint32_t c1 = cvtpk(p[8], p[9]), c2 = cvtpk(p[10], p[11]);
      uint32_t d1 = cvtpk(p[12], p[13]), d2 = cvtpk(p[14], p[15]);
      uint32_t sa1 = (uint32_t)__shfl_xor((int)a1, 32), sa2 = (uint32_t)__shfl_xor((int)a2, 32);
      uint32_t sb1 = (uint32_t)__shfl_xor((int)b1, 32), sb2 = (uint32_t)__shfl_xor((int)b2, 32);
      uint32_t sc1 = (uint32_t)__shfl_xor((int)c1, 32), sc2 = (uint32_t)__shfl_xor((int)c2, 32);
      uint32_t sd1 = (uint32_t)__shfl_xor((int)d1, 32), sd2 = (uint32_t)__shfl_xor((int)d2, 32);
      union { uint32_t u[4]; short8 s8v; } pu0, pu1;
      pu0.u[0] = hi ? sb1 : a1;  pu0.u[1] = hi ? sb2 : a2;
      pu0.u[2] = hi ? b1 : sa1;  pu0.u[3] = hi ? b2 : sa2;
      pu1.u[0] = hi ? sd1 : c1;  pu1.u[1] = hi ? sd2 : c2;
      pu1.u[2] = hi ? d1 : sc1;  pu1.u[3] = hi ? d2 : sc2;
      short8 pf0 = pu0.s8v, pf1 = pu1.s8v;

#pragma unroll
      for (int d = 0; d < 4; ++d) {
        const u16* vb0 = &Vsm[(d * 32 + q) * KROW + st * 32 + hi * 8];
        short8 vf0 = ld8(vb0);
        short8 vf1 = ld8(vb0 + 16);
        acc[d] = mfma32(vf0, pf0, acc[d]);
        acc[d] = mfma32(vf1, pf1, acc[d]);
      }
    }
  }

  float L = Lp + __shfl_xor(Lp, 32);
  float inv = 1.f / L;
  __syncthreads();  // staging dead -> Ysm overlay safe
  if (stream == 1) {
    u16* yrow = &Ysm[(pair * 64 + l) * YROW];
#pragma unroll
    for (int d = 0; d < 4; ++d) {
      union { uint32_t u[8]; short8 v[2]; } pk;
#pragma unroll
      for (int i = 0; i < 8; ++i)
        pk.u[i] = cvtpk(acc[d][2 * i] * inv, acc[d][2 * i + 1] * inv);
      st8(yrow + d * 16, pk.v[0]);
      st8(yrow + d * 16 + 8, pk.v[1]);
    }
  }
  __syncthreads();
  if (stream == 0) {
    const u16* yrow = &Ysm[(pair * 64 + l) * YROW];
    float y[4][16];
#pragma unroll
    for (int d = 0; d < 4; ++d) {
      short8 y2a = ld8(yrow + d * 16);
      short8 y2b = ld8(yrow + d * 16 + 8);
#pragma unroll
      for (int i = 0; i < 8; ++i) {
        y[d][i] = acc[d][i] * inv - lam * b2f((u16)y2a[i]);
        y[d][8 + i] = acc[d][8 + i] * inv - lam * b2f((u16)y2b[i]);
      }
    }
    float sm = 0.f;
#pragma unroll
    for (int d = 0; d < 4; ++d)
#pragma unroll
      for (int r = 0; r < 16; ++r) sm += y[d][r];
    sm += __shfl_xor(sm, 32);
    float u = sm * (1.f / 128.f);
    float var = 0.f;
#pragma unroll
    for (int d = 0; d < 4; ++d)
#pragma unroll
      for (int r = 0; r < 16; ++r) { float dd = y[d][r] - u; var += dd * dd; }
    var += __shfl_xor(var, 32);
    float rstd = rsqrtf(var * (1.f / 128.f) + 1e-12f);

    size_t orow = (size_t)(b * T_SEQ + qr0 + q) * 2048 + h * 128;
#pragma unroll
    for (int d = 0; d < 4; ++d)
#pragma unroll
      for (int rr = 0; rr < 4; ++rr) {
        int base = d * 32 + 8 * rr + 4 * hi;
        union { u16 u[4]; uint2 v; } o;
#pragma unroll
        for (int i = 0; i < 4; ++i) {
          float yv = (lnw[base + i] * ((y[d][rr * 4 + i] - u) * rstd) + lnb[base + i]) *
                     ONE_MINUS_LI;
          o.u[i] = f2bf(yv);
        }
        *reinterpret_cast<uint2*>(&yout[orow + base]) = o.v;
      }
  }
}

// ---------------- host ----------------
extern "C" void kernel_launch(void* const* d_in, const int* in_sizes, int n_in,
                              void* d_out, int out_size, void* d_ws, size_t ws_size,
                              hipStream_t stream) {
  (void)in_sizes; (void)n_in; (void)out_size; (void)ws_size;
  const float* q   = (const float*)d_in[0];
  const float* k   = (const float*)d_in[1];
  const float* v   = (const float*)d_in[2];
  const int* maskp = (const int*)d_in[3];
  const float* Wq1 = (const float*)d_in[4];
  const float* bq1 = (const float*)d_in[5];
  const float* Wq2 = (const float*)d_in[6];
  const float* bq2 = (const float*)d_in[7];
  const float* Wk1 = (const float*)d_in[8];
  const float* bk1 = (const float*)d_in[9];
  const float* Wk2 = (const float*)d_in[10];
  const float* bk2 = (const float*)d_in[11];
  const float* Wv  = (const float*)d_in[12];
  const float* bv  = (const float*)d_in[13];
  const float* Wc  = (const float*)d_in[14];
  const float* bc  = (const float*)d_in[15];
  const float* lnw = (const float*)d_in[16];
  const float* lnb = (const float*)d_in[17];
  const float* lq1 = (const float*)d_in[18];
  const float* lk1 = (const float*)d_in[19];
  const float* lq2 = (const float*)d_in[20];
  const float* lk2 = (const float*)d_in[21];

  char* ws = (char*)d_ws;
  u16* qb     = (u16*)(ws + 0);          // qb|kb|vb contiguous [12288][1024]
  u16* Wq12T  = (u16*)(ws + 25165824);   // Wq12T|Wk12T|WvT contiguous [6144][1024]
  u16* WvT    = (u16*)(ws + 33554432);
  u16* WcT    = (u16*)(ws + 37748736);
  u16* q1q2   = (u16*)(ws + 41959424);   // q1q2|kT|vvT contiguous
  u16* kT     = (u16*)(ws + 58736640);
  u16* vvT    = (u16*)(ws + 75513856);
  u16* yb     = (u16*)(ws + 0);  // alias qb+kb (16MB; both dead before attention)

  const int NELEM = 2 * T_SEQ * 1024;  // 4,194,304

  cvt3_bf16<<<12288, 256, 0, stream>>>(q, k, v, qb, NELEM);

  tcvt6<<<8192, 256, 0, stream>>>(Wq1, Wq2, Wk1, Wk2, Wv, Wc, Wq12T, WvT, WcT);

  // ONE projection GEMM: M=12288 over qb|kb|vb; epilogues q1q2 / kT / vvT
  gemm_proj<<<dim3(16, 96), 256, 0, stream>>>(qb, Wq12T, bq1, bq2, bk1, bk2, bv,
                                              q1q2, 12288, 2048, 1024);

  diffattn<<<1024, 256, 0, stream>>>(q1q2, kT, vvT, maskp,
                                     lq1, lk1, lq2, lk2, lnw, lnb, yb);

  // final GEMM: 128x64 tile, 512 blocks = 2/CU
  gemm_fin<<<dim3(16, 32), 256, 0, stream>>>(yb, WcT, bc, (float*)d_out,
                                             4096, 1024, 2048);
}